// Round 1
// baseline (404.501 us; speedup 1.0000x reference)
//
#include <hip/hip_runtime.h>

// ---------------------------------------------------------------------------
// SJCSNN: conv1+bn1 -> IF -> pool -> conv2+bn2 -> IF -> pool -> fc1 -> LIF ->
//         fc2 -> LIF -> fc3 -> LIF -> mean over T.
// T=8, B=32. All spike tensors are binary => exact in bf16 => MFMA with
// hi/lo-split fp32 weights gives fp32-class accuracy at bf16 MFMA rate.
// ---------------------------------------------------------------------------

typedef float  f32x4  __attribute__((ext_vector_type(4)));
typedef __bf16 bf16x8 __attribute__((ext_vector_type(8)));
typedef short  short8 __attribute__((ext_vector_type(8)));

#define T_STEPS 8
#define BATCH 32

// ---- workspace layout (bytes). Regions reused across pipeline phases. ----
// p1pad [8][32][26][26][128] bf16 : 44,302,336   (dead after conv2 -> reused by fc1 partials)
// y2    [8][32][24][24][128] f32  : 75,497,472   (dead after if2_pool -> reused by l1pre/l1s/l2pre/l2s)
// wt    hi+lo [9][128][128] bf16  :    589,824
// p2    [8][32][128][12][12] bf16 :  9,437,184
// w2t   [1152][128] f32           :    589,824
static const size_t OFF_P1    = 0;                     // 44,302,336
static const size_t OFF_PART  = 0;                     // 37,748,736 (reuse)
static const size_t OFF_Y2    = 44302336;              // 75,497,472
static const size_t OFF_L1PRE = 44302336;              //  1,179,648 (reuse)
static const size_t OFF_L1S   = 45481984;              //  1,179,648
static const size_t OFF_L2PRE = 46661632;              //    131,072
static const size_t OFF_L2S   = 46792704;              //    131,072
static const size_t OFF_WT    = 119799808;             //    589,824
static const size_t OFF_P2    = 120389632;             //  9,437,184
static const size_t OFF_W2T   = 129826816;             //    589,824  (end 130,416,640)

__device__ __forceinline__ unsigned short bf16_rne(float f) {
  unsigned u = __builtin_bit_cast(unsigned, f);
  u += 0x7FFFu + ((u >> 16) & 1u);
  return (unsigned short)(u >> 16);
}
__device__ __forceinline__ float bf16_to_f(unsigned short h) {
  unsigned u = ((unsigned)h) << 16;
  return __builtin_bit_cast(float, u);
}

// direct-to-LDS 16B load (CK-style address-space casts)
__device__ __forceinline__ void lds_load16(const void* g, void* l) {
  auto* gp = reinterpret_cast<const __attribute__((address_space(1))) unsigned int*>(
      reinterpret_cast<uintptr_t>(g));
  auto* lp = reinterpret_cast<__attribute__((address_space(3))) unsigned int*>(
      reinterpret_cast<uintptr_t>(l));
  __builtin_amdgcn_global_load_lds(gp, lp, 16, 0, 0);
}

// ---------------------------------------------------------------------------
__global__ __launch_bounds__(256) void zerofill(uint4* p, int n4) {
  int i = blockIdx.x * 256 + threadIdx.x;
  if (i < n4) p[i] = make_uint4(0u, 0u, 0u, 0u);
}

// repack conv2_w -> wt[tap][oc][ic] bf16 hi/lo; transpose fc2_w -> w2t[k][o]
__global__ __launch_bounds__(256) void prep_weights(const float* __restrict__ conv2_w,
                                                    const float* __restrict__ fc2_w,
                                                    short* __restrict__ wt_hi,
                                                    short* __restrict__ wt_lo,
                                                    float* __restrict__ w2t) {
  int i = blockIdx.x * 256 + threadIdx.x;           // 0 .. 294911
  if (i < 147456) {
    int tap = i >> 14;                              // /16384
    int oc  = (i >> 7) & 127;
    int ic  = i & 127;
    float wv = conv2_w[oc * 1152 + ic * 9 + tap];
    unsigned short h = bf16_rne(wv);
    float lf = wv - bf16_to_f(h);
    wt_hi[i] = (short)h;
    wt_lo[i] = (short)bf16_rne(lf);
  } else {
    int j = i - 147456;
    int o = j & 127, k = j >> 7;
    w2t[j] = fc2_w[o * 1152 + k];
  }
}

// conv1(1->128,3x3,SAME)+bn1 -> IF over T (same input each step) -> 2x2 maxpool
// writes p1pad [t][b][1+oy][1+ox][c] bf16 spikes (borders pre-zeroed)
__global__ __launch_bounds__(128) void conv1_if_pool(
    const float* __restrict__ x, const float* __restrict__ w1, const float* __restrict__ b1,
    const float* __restrict__ g1, const float* __restrict__ be1, const float* __restrict__ m1,
    const float* __restrict__ vv1, short* __restrict__ p1) {
  __shared__ float patch[16];
  const int c  = threadIdx.x;
  const int sp = blockIdx.x;                        // 0..575
  const int b  = blockIdx.y;
  const int oy = sp / 24, ox = sp % 24;
  if (c < 16) {
    int py = c >> 2, px = c & 3;
    int iy = 2 * oy - 1 + py, ix = 2 * ox - 1 + px;
    float v = 0.f;
    if (iy >= 0 && iy < 48 && ix >= 0 && ix < 48) v = x[b * 2304 + iy * 48 + ix];
    patch[c] = v;
  }
  __syncthreads();
  float w[9];
#pragma unroll
  for (int i = 0; i < 9; ++i) w[i] = w1[c * 9 + i];
  float scale = g1[c] * rsqrtf(vv1[c] + 1e-5f);
  float shift = (b1[c] - m1[c]) * scale + be1[c];
  float h[4];
#pragma unroll
  for (int p = 0; p < 4; ++p) {
    int py = p >> 1, px = p & 1;
    float s = 0.f;
#pragma unroll
    for (int dy = 0; dy < 3; ++dy)
#pragma unroll
      for (int dx = 0; dx < 3; ++dx) s += patch[(py + dy) * 4 + (px + dx)] * w[dy * 3 + dx];
    h[p] = s * scale + shift;
  }
  float va = 0.f, vb = 0.f, vc = 0.f, vd = 0.f;
  size_t base = ((size_t)b * 676 + (size_t)(1 + oy) * 26 + (1 + ox)) * 128 + c;
#pragma unroll
  for (int t = 0; t < T_STEPS; ++t) {
    va += h[0]; vb += h[1]; vc += h[2]; vd += h[3];
    bool s0 = va >= 1.f, s1 = vb >= 1.f, s2 = vc >= 1.f, s3 = vd >= 1.f;
    p1[base + (size_t)t * (32 * 676 * 128)] = (s0 | s1 | s2 | s3) ? (short)0x3F80 : (short)0;
    if (s0) va = 0.f; if (s1) vb = 0.f; if (s2) vc = 0.f; if (s3) vd = 0.f;
  }
}

// conv2 as implicit-im2col MFMA GEMM: M=147456 (t,b,y,x), N=128 (oc), K=9 taps x 128 ic.
// A = padded NHWC spikes (bf16 exact); B = wt hi+lo (split fp32). Epilogue folds bn2.
__global__ __launch_bounds__(256) void conv2_gemm(
    const short* __restrict__ p1pad, const short* __restrict__ wt_hi, const short* __restrict__ wt_lo,
    const float* __restrict__ conv2_b, const float* __restrict__ bn2_g, const float* __restrict__ bn2_b,
    const float* __restrict__ bn2_m, const float* __restrict__ bn2_v, float* __restrict__ y2) {
  __shared__ __align__(16) short lds[24576];        // A:8192  Bh:8192  Bl:8192 (shorts)
  short* ldsA = lds;
  short* ldsBh = lds + 8192;
  short* ldsBl = lds + 16384;

  const int tid = threadIdx.x;
  const int lane = tid & 63;
  const int w = tid >> 6;                           // 0..3
  const int wm = w & 1, wn = w >> 1;
  const int m0 = blockIdx.x * 128;

  // staging: lane covers row r = w*32+j*8+(lane>>3), swizzled chunk g = (lane&7)^(lane>>3)
  const int g = (lane & 7) ^ (lane >> 3);
  int rowofs[4], bofs[4];
#pragma unroll
  for (int j = 0; j < 4; ++j) {
    int r = w * 32 + j * 8 + (lane >> 3);
    int m = m0 + r;
    int tb = m / 576;
    int rem = m - tb * 576;
    int yy = rem / 24;
    int xx = rem - yy * 24;
    rowofs[j] = (tb * 676 + yy * 26 + xx) * 128 + g * 8;
    bofs[j] = r * 128 + g * 8;
  }

  f32x4 acc[4][4];
#pragma unroll
  for (int mi = 0; mi < 4; ++mi)
#pragma unroll
    for (int ni = 0; ni < 4; ++ni) acc[mi][ni] = (f32x4){0.f, 0.f, 0.f, 0.f};

#pragma unroll 1
  for (int s = 0; s < 18; ++s) {
    const int tap = s >> 1;
    const int kk = (s & 1) << 6;
    const int tapoff = ((tap / 3) * 26 + (tap % 3)) * 128;
    __syncthreads();
#pragma unroll
    for (int j = 0; j < 4; ++j) {
      lds_load16(p1pad + rowofs[j] + tapoff + kk, ldsA + (w * 32 + j * 8) * 64 + lane * 8);
    }
    const int wtoff = tap * 16384 + kk;
#pragma unroll
    for (int j = 0; j < 4; ++j) {
      lds_load16(wt_hi + wtoff + bofs[j], ldsBh + (w * 32 + j * 8) * 64 + lane * 8);
      lds_load16(wt_lo + wtoff + bofs[j], ldsBl + (w * 32 + j * 8) * 64 + lane * 8);
    }
    __syncthreads();
#pragma unroll
    for (int ks = 0; ks < 2; ++ks) {
      bf16x8 a[4], bh[4], bl[4];
      const int cch = ks * 4 + (lane >> 4);
#pragma unroll
      for (int i = 0; i < 4; ++i) {
        int r = wm * 64 + i * 16 + (lane & 15);
        a[i] = *(const bf16x8*)(ldsA + r * 64 + ((cch ^ (r & 7)) * 8));
        int n = wn * 64 + i * 16 + (lane & 15);
        bh[i] = *(const bf16x8*)(ldsBh + n * 64 + ((cch ^ (n & 7)) * 8));
        bl[i] = *(const bf16x8*)(ldsBl + n * 64 + ((cch ^ (n & 7)) * 8));
      }
#pragma unroll
      for (int mi = 0; mi < 4; ++mi)
#pragma unroll
        for (int ni = 0; ni < 4; ++ni) {
          acc[mi][ni] = __builtin_amdgcn_mfma_f32_16x16x32_bf16(a[mi], bh[ni], acc[mi][ni], 0, 0, 0);
          acc[mi][ni] = __builtin_amdgcn_mfma_f32_16x16x32_bf16(a[mi], bl[ni], acc[mi][ni], 0, 0, 0);
        }
    }
  }
  // epilogue: bn2 fold; C/D map: m = (lane>>4)*4+reg, n = lane&15 (m89-verified)
#pragma unroll
  for (int ni = 0; ni < 4; ++ni) {
    int oc = wn * 64 + ni * 16 + (lane & 15);
    float sc = bn2_g[oc] * rsqrtf(bn2_v[oc] + 1e-5f);
    float sh = (conv2_b[oc] - bn2_m[oc]) * sc + bn2_b[oc];
#pragma unroll
    for (int mi = 0; mi < 4; ++mi) {
#pragma unroll
      for (int r = 0; r < 4; ++r) {
        int m = m0 + wm * 64 + mi * 16 + ((lane >> 4) << 2) + r;
        y2[(size_t)m * 128 + oc] = acc[mi][ni][r] * sc + sh;
      }
    }
  }
}

// IF over T on y2 (NHWC) + 2x2 maxpool -> p2 [t][b][oc][12][12] bf16 (== fc1 A rows)
__global__ __launch_bounds__(128) void if2_pool(const float* __restrict__ y2, short* __restrict__ p2) {
  const int oc = threadIdx.x;
  const int gid = blockIdx.x;                       // 0..35 : oy(12) x quad(3)
  const int b = blockIdx.y;
  const int oy = gid / 3;
  const int ox0 = (gid % 3) * 4;
  float v[16];
#pragma unroll
  for (int i = 0; i < 16; ++i) v[i] = 0.f;
#pragma unroll
  for (int t = 0; t < T_STEPS; ++t) {
    const float* base = y2 + ((size_t)(t * 32 + b) * 576) * 128 + oc;
    bool sp[16];
#pragma unroll
    for (int row = 0; row < 2; ++row) {
      int iy = 2 * oy + row;
#pragma unroll
      for (int col = 0; col < 8; ++col) {
        int ix = 2 * ox0 + col;
        float xx = base[(size_t)(iy * 24 + ix) * 128];
        int idx = row * 8 + col;
        v[idx] += xx;
        bool s = v[idx] >= 1.f;
        sp[idx] = s;
        if (s) v[idx] = 0.f;
      }
    }
    ushort4 o4;
    o4.x = (sp[0] | sp[1] | sp[8]  | sp[9])  ? 0x3F80 : 0;
    o4.y = (sp[2] | sp[3] | sp[10] | sp[11]) ? 0x3F80 : 0;
    o4.z = (sp[4] | sp[5] | sp[12] | sp[13]) ? 0x3F80 : 0;
    o4.w = (sp[6] | sp[7] | sp[14] | sp[15]) ? 0x3F80 : 0;
    *(ushort4*)((unsigned short*)p2 + ((size_t)(t * 32 + b) * 128 + oc) * 144 + oy * 12 + ox0) = o4;
  }
}

// fc1: M=256 (one tile), N=1152 (9 tiles), K=18432 split 32 ways.
// A = p2 spikes bf16; B = fc1_w fp32 converted to hi/lo bf16 on the fly into LDS.
__global__ __launch_bounds__(512) void fc1_gemm(const short* __restrict__ p2,
                                                const float* __restrict__ fc1_w,
                                                float* __restrict__ part) {
  __shared__ __align__(16) short lds[32768];        // A:16384  Bh:8192  Bl:8192
  short* ldsA = lds;
  short* ldsBh = lds + 16384;
  short* ldsBl = lds + 24576;

  const int tid = threadIdx.x;
  const int lane = tid & 63;
  const int w = tid >> 6;                           // 0..7
  const int wm = w & 3, wn = w >> 2;
  const int n0 = blockIdx.x * 128;
  const int kb = blockIdx.y * 576;

  const int g = (lane & 7) ^ (lane >> 3);
  int aofs[4];
#pragma unroll
  for (int j = 0; j < 4; ++j) {
    int r = w * 32 + j * 8 + (lane >> 3);
    aofs[j] = r * 18432 + g * 8;
  }
  const int bn = tid >> 2;                          // 0..127 (B row)
  const int c0 = (tid & 3) * 2;                     // chunk pair 0,2,4,6
  const float* wrow = fc1_w + (size_t)(n0 + bn) * 18432 + c0 * 8;
  const int bpos0 = (c0 ^ (bn & 7)) * 8;
  const int bpos1 = ((c0 + 1) ^ (bn & 7)) * 8;

  f32x4 acc[4][4];
#pragma unroll
  for (int mi = 0; mi < 4; ++mi)
#pragma unroll
    for (int ni = 0; ni < 4; ++ni) acc[mi][ni] = (f32x4){0.f, 0.f, 0.f, 0.f};

#pragma unroll 1
  for (int s = 0; s < 9; ++s) {
    const int koff = kb + s * 64;
    __syncthreads();
#pragma unroll
    for (int j = 0; j < 4; ++j) {
      lds_load16(p2 + aofs[j] + koff, ldsA + (w * 32 + j * 8) * 64 + lane * 8);
    }
    {
      const float4* wp = (const float4*)(wrow + koff);
      float4 q0 = wp[0], q1 = wp[1], q2 = wp[2], q3 = wp[3];
      float fv[16] = {q0.x, q0.y, q0.z, q0.w, q1.x, q1.y, q1.z, q1.w,
                      q2.x, q2.y, q2.z, q2.w, q3.x, q3.y, q3.z, q3.w};
      short8 h0, h1, l0, l1;
#pragma unroll
      for (int q = 0; q < 8; ++q) {
        unsigned short hh = bf16_rne(fv[q]);
        h0[q] = (short)hh;
        l0[q] = (short)bf16_rne(fv[q] - bf16_to_f(hh));
      }
#pragma unroll
      for (int q = 0; q < 8; ++q) {
        unsigned short hh = bf16_rne(fv[8 + q]);
        h1[q] = (short)hh;
        l1[q] = (short)bf16_rne(fv[8 + q] - bf16_to_f(hh));
      }
      *(short8*)(ldsBh + bn * 64 + bpos0) = h0;
      *(short8*)(ldsBh + bn * 64 + bpos1) = h1;
      *(short8*)(ldsBl + bn * 64 + bpos0) = l0;
      *(short8*)(ldsBl + bn * 64 + bpos1) = l1;
    }
    __syncthreads();
#pragma unroll
    for (int ks = 0; ks < 2; ++ks) {
      bf16x8 a[4], bh[4], bl[4];
      const int cch = ks * 4 + (lane >> 4);
#pragma unroll
      for (int i = 0; i < 4; ++i) {
        int r = wm * 64 + i * 16 + (lane & 15);
        a[i] = *(const bf16x8*)(ldsA + r * 64 + ((cch ^ (r & 7)) * 8));
        int n = wn * 64 + i * 16 + (lane & 15);
        bh[i] = *(const bf16x8*)(ldsBh + n * 64 + ((cch ^ (n & 7)) * 8));
        bl[i] = *(const bf16x8*)(ldsBl + n * 64 + ((cch ^ (n & 7)) * 8));
      }
#pragma unroll
      for (int mi = 0; mi < 4; ++mi)
#pragma unroll
        for (int ni = 0; ni < 4; ++ni) {
          acc[mi][ni] = __builtin_amdgcn_mfma_f32_16x16x32_bf16(a[mi], bh[ni], acc[mi][ni], 0, 0, 0);
          acc[mi][ni] = __builtin_amdgcn_mfma_f32_16x16x32_bf16(a[mi], bl[ni], acc[mi][ni], 0, 0, 0);
        }
    }
  }
  const size_t pbase = (size_t)(blockIdx.y * 9 + blockIdx.x) * 32768;  // 256*128
#pragma unroll
  for (int ni = 0; ni < 4; ++ni) {
    int j = wn * 64 + ni * 16 + (lane & 15);
#pragma unroll
    for (int mi = 0; mi < 4; ++mi) {
#pragma unroll
      for (int r = 0; r < 4; ++r) {
        int m = wm * 64 + mi * 16 + ((lane >> 4) << 2) + r;
        part[pbase + (size_t)m * 128 + j] = acc[mi][ni][r];
      }
    }
  }
}

__global__ __launch_bounds__(256) void fc1_reduce(const float* __restrict__ part,
                                                  const float* __restrict__ fc1_b,
                                                  float* __restrict__ l1pre) {
  int i = blockIdx.x * 256 + threadIdx.x;           // < 294912
  int m = i / 1152, n = i - m * 1152;
  int nt = n >> 7, j = n & 127;
  float s = fc1_b[n];
#pragma unroll 4
  for (int ks = 0; ks < 32; ++ks) s += part[(((size_t)ks * 9 + nt) * 256 + m) * 128 + j];
  l1pre[i] = s;
}

// LIF over T (decay_input, tau=2, hard reset): pre [t][nper] -> spikes [t][nper]
__global__ __launch_bounds__(256) void lif_kernel(const float* __restrict__ pre,
                                                  float* __restrict__ spk, int nper) {
  int i = blockIdx.x * 256 + threadIdx.x;
  if (i >= nper) return;
  float v = 0.f;
#pragma unroll
  for (int t = 0; t < T_STEPS; ++t) {
    float xx = pre[(size_t)t * nper + i];
    v += (xx - v) * 0.5f;
    bool s = v >= 1.f;
    spk[(size_t)t * nper + i] = s ? 1.f : 0.f;
    if (s) v = 0.f;
  }
}

// fc2: [256,1152] spikes @ w2t[k][o] -> l2pre [256][128]
__global__ __launch_bounds__(128) void fc2_kernel(const float* __restrict__ l1s,
                                                  const float* __restrict__ w2t,
                                                  const float* __restrict__ b2,
                                                  float* __restrict__ l2pre) {
  __shared__ float sx[4608];
  const int tid = threadIdx.x;
  const int m0 = blockIdx.x * 4;
  for (int i = tid; i < 4608; i += 128) sx[i] = l1s[(size_t)m0 * 1152 + i];
  __syncthreads();
  float a0 = 0.f, a1 = 0.f, a2 = 0.f, a3 = 0.f;
  for (int k = 0; k < 1152; ++k) {
    float wv = w2t[k * 128 + tid];
    a0 += sx[k] * wv;
    a1 += sx[1152 + k] * wv;
    a2 += sx[2304 + k] * wv;
    a3 += sx[3456 + k] * wv;
  }
  float bb = b2[tid];
  l2pre[(size_t)(m0 + 0) * 128 + tid] = a0 + bb;
  l2pre[(size_t)(m0 + 1) * 128 + tid] = a1 + bb;
  l2pre[(size_t)(m0 + 2) * 128 + tid] = a2 + bb;
  l2pre[(size_t)(m0 + 3) * 128 + tid] = a3 + bb;
}

// fc3 + LIF + mean over T. One wave per (o,b).
__global__ __launch_bounds__(64) void fc3_tail(const float* __restrict__ l2s,
                                               const float* __restrict__ w3,
                                               const float* __restrict__ b3,
                                               float* __restrict__ out) {
  const int o = blockIdx.x, b = blockIdx.y;
  const int lane = threadIdx.x;
  float wa = w3[o * 128 + lane], wb = w3[o * 128 + 64 + lane];
  float bias = b3[o];
  float v = 0.f, accum = 0.f;
#pragma unroll
  for (int t = 0; t < T_STEPS; ++t) {
    const float* row = l2s + ((size_t)t * 32 + b) * 128;
    float p = row[lane] * wa + row[64 + lane] * wb;
#pragma unroll
    for (int msk = 32; msk > 0; msk >>= 1) p += __shfl_xor(p, msk);
    float xx = p + bias;
    v += (xx - v) * 0.5f;
    bool s = v >= 1.f;
    accum += s ? 1.f : 0.f;
    if (s) v = 0.f;
  }
  if (lane == 0) out[b * 7 + o] = accum * 0.125f;
}

// ---------------------------------------------------------------------------
extern "C" void kernel_launch(void* const* d_in, const int* in_sizes, int n_in,
                              void* d_out, int out_size, void* d_ws, size_t ws_size,
                              hipStream_t stream) {
  const float* x       = (const float*)d_in[0];
  const float* conv1_w = (const float*)d_in[1];
  const float* conv1_b = (const float*)d_in[2];
  const float* bn1_g   = (const float*)d_in[3];
  const float* bn1_b   = (const float*)d_in[4];
  const float* bn1_m   = (const float*)d_in[5];
  const float* bn1_v   = (const float*)d_in[6];
  const float* conv2_w = (const float*)d_in[7];
  const float* conv2_b = (const float*)d_in[8];
  const float* bn2_g   = (const float*)d_in[9];
  const float* bn2_b   = (const float*)d_in[10];
  const float* bn2_m   = (const float*)d_in[11];
  const float* bn2_v   = (const float*)d_in[12];
  const float* fc1_w   = (const float*)d_in[13];
  const float* fc1_b   = (const float*)d_in[14];
  const float* fc2_w   = (const float*)d_in[15];
  const float* fc2_b   = (const float*)d_in[16];
  const float* fc3_w   = (const float*)d_in[17];
  const float* fc3_b   = (const float*)d_in[18];

  char* ws = (char*)d_ws;
  short* p1pad = (short*)(ws + OFF_P1);
  float* y2    = (float*)(ws + OFF_Y2);
  short* wt_hi = (short*)(ws + OFF_WT);
  short* wt_lo = wt_hi + 147456;
  short* p2    = (short*)(ws + OFF_P2);
  float* part  = (float*)(ws + OFF_PART);
  float* l1pre = (float*)(ws + OFF_L1PRE);
  float* l1s   = (float*)(ws + OFF_L1S);
  float* l2pre = (float*)(ws + OFF_L2PRE);
  float* l2s   = (float*)(ws + OFF_L2S);
  float* w2t   = (float*)(ws + OFF_W2T);
  float* out   = (float*)d_out;

  zerofill<<<10816, 256, 0, stream>>>((uint4*)p1pad, 2768896);
  prep_weights<<<1152, 256, 0, stream>>>(conv2_w, fc2_w, wt_hi, wt_lo, w2t);
  conv1_if_pool<<<dim3(576, 32), 128, 0, stream>>>(x, conv1_w, conv1_b, bn1_g, bn1_b, bn1_m, bn1_v, p1pad);
  conv2_gemm<<<1152, 256, 0, stream>>>(p1pad, wt_hi, wt_lo, conv2_b, bn2_g, bn2_b, bn2_m, bn2_v, y2);
  if2_pool<<<dim3(36, 32), 128, 0, stream>>>(y2, p2);
  fc1_gemm<<<dim3(9, 32), 512, 0, stream>>>(p2, fc1_w, part);
  fc1_reduce<<<1152, 256, 0, stream>>>(part, fc1_b, l1pre);
  lif_kernel<<<144, 256, 0, stream>>>(l1pre, l1s, 36864);
  fc2_kernel<<<64, 128, 0, stream>>>(l1s, w2t, fc2_b, l2pre);
  lif_kernel<<<16, 256, 0, stream>>>(l2pre, l2s, 4096);
  fc3_tail<<<dim3(7, 32), 64, 0, stream>>>(l2s, fc3_w, fc3_b, out);
}

// Round 2
// 392.877 us; speedup vs baseline: 1.0296x; 1.0296x over previous
//
#include <hip/hip_runtime.h>

// ---------------------------------------------------------------------------
// SJCSNN: conv1+bn1 -> IF -> pool -> conv2+bn2 -> IF -> pool -> fc1 -> LIF ->
//         fc2 -> LIF -> fc3 -> LIF -> mean over T.  T=8, B=32.
// Spikes are binary => exact in bf16 => MFMA with hi/lo-split fp32 weights
// gives fp32-identical threshold decisions (R1: absmax == 0.0).
// R2: conv2 retiled so each block owns all 8 t of 4 pool quads -> IF+pool
// fused into the epilogue (y2 never materialized, -150 MB HBM, -1 kernel);
// border-only pad zeroing; reduce+LIF and LIF+fc3 fused.
// ---------------------------------------------------------------------------

typedef float  f32x4  __attribute__((ext_vector_type(4)));
typedef __bf16 bf16x8 __attribute__((ext_vector_type(8)));
typedef short  short8 __attribute__((ext_vector_type(8)));

#define T_STEPS 8

// ---- workspace layout (bytes) ----
// p1pad [8][32][26][26][128] bf16 : 44,302,336  (dead after conv2 -> fc1 partials reuse)
static const size_t OFF_P1    = 0;
static const size_t OFF_PART  = 0;                  // 37,748,736 (reuse of p1pad)
static const size_t OFF_WT    = 44302336;           //    589,824 (hi+lo conv2 weights)
static const size_t OFF_P2    = 44892160;           //  9,437,184
static const size_t OFF_W2T   = 54329344;           //    589,824
static const size_t OFF_L1S   = 54919168;           //  1,179,648
static const size_t OFF_L2PRE = 56098816;           //    131,072   (end 56,229,888)

__device__ __forceinline__ unsigned short bf16_rne(float f) {
  unsigned u = __builtin_bit_cast(unsigned, f);
  u += 0x7FFFu + ((u >> 16) & 1u);
  return (unsigned short)(u >> 16);
}
__device__ __forceinline__ float bf16_to_f(unsigned short h) {
  unsigned u = ((unsigned)h) << 16;
  return __builtin_bit_cast(float, u);
}

__device__ __forceinline__ void lds_load16(const void* g, void* l) {
  auto* gp = reinterpret_cast<const __attribute__((address_space(1))) unsigned int*>(
      reinterpret_cast<uintptr_t>(g));
  auto* lp = reinterpret_cast<__attribute__((address_space(3))) unsigned int*>(
      reinterpret_cast<uintptr_t>(l));
  __builtin_amdgcn_global_load_lds(gp, lp, 16, 0, 0);
}

// ---------------------------------------------------------------------------
// prep: conv2_w -> wt[tap][oc][ic] bf16 hi/lo; fc2_w transpose; p1pad border zero.
__global__ __launch_bounds__(256) void prep(const float* __restrict__ conv2_w,
                                            const float* __restrict__ fc2_w,
                                            short* __restrict__ wt_hi,
                                            short* __restrict__ wt_lo,
                                            float* __restrict__ w2t,
                                            uint4* __restrict__ p1pad4) {
  int i = blockIdx.x * 256 + threadIdx.x;            // < 704512
  if (i < 147456) {
    int tap = i >> 14;
    int oc  = (i >> 7) & 127;
    int ic  = i & 127;
    float wv = conv2_w[oc * 1152 + ic * 9 + tap];
    unsigned short h = bf16_rne(wv);
    wt_hi[i] = (short)h;
    wt_lo[i] = (short)bf16_rne(wv - bf16_to_f(h));
  } else if (i < 294912) {
    int j = i - 147456;
    int o = j & 127, k = j >> 7;
    w2t[j] = fc2_w[o * 1152 + k];
  } else if (i < 704512) {
    int k = i - 294912;                              // 256 tb x 100 border pos x 16 uint4
    int tb = k / 1600;
    int rem = k - tb * 1600;
    int pos = rem >> 4, c8 = rem & 15;
    int y, x;
    if (pos < 26)      { y = 0;  x = pos; }
    else if (pos < 52) { y = 25; x = pos - 26; }
    else { int jj = pos - 52; y = 1 + (jj >> 1); x = (jj & 1) * 25; }
    p1pad4[(tb * 676 + y * 26 + x) * 16 + c8] = make_uint4(0u, 0u, 0u, 0u);
  }
}

// conv1(1->128,3x3,SAME)+bn1 -> IF over T (same drive each step) -> 2x2 maxpool
// writes p1pad [t][b][1+oy][1+ox][c] bf16 spikes (borders pre-zeroed by prep)
__global__ __launch_bounds__(128) void conv1_if_pool(
    const float* __restrict__ x, const float* __restrict__ w1, const float* __restrict__ b1,
    const float* __restrict__ g1, const float* __restrict__ be1, const float* __restrict__ m1,
    const float* __restrict__ vv1, short* __restrict__ p1) {
  __shared__ float patch[16];
  const int c  = threadIdx.x;
  const int sp = blockIdx.x;                        // 0..575
  const int b  = blockIdx.y;
  const int oy = sp / 24, ox = sp % 24;
  if (c < 16) {
    int py = c >> 2, px = c & 3;
    int iy = 2 * oy - 1 + py, ix = 2 * ox - 1 + px;
    float v = 0.f;
    if (iy >= 0 && iy < 48 && ix >= 0 && ix < 48) v = x[b * 2304 + iy * 48 + ix];
    patch[c] = v;
  }
  __syncthreads();
  float w[9];
#pragma unroll
  for (int i = 0; i < 9; ++i) w[i] = w1[c * 9 + i];
  float scale = g1[c] * rsqrtf(vv1[c] + 1e-5f);
  float shift = (b1[c] - m1[c]) * scale + be1[c];
  float h[4];
#pragma unroll
  for (int p = 0; p < 4; ++p) {
    int py = p >> 1, px = p & 1;
    float s = 0.f;
#pragma unroll
    for (int dy = 0; dy < 3; ++dy)
#pragma unroll
      for (int dx = 0; dx < 3; ++dx) s += patch[(py + dy) * 4 + (px + dx)] * w[dy * 3 + dx];
    h[p] = s * scale + shift;
  }
  float va = 0.f, vb = 0.f, vc = 0.f, vd = 0.f;
  size_t base = ((size_t)b * 676 + (size_t)(1 + oy) * 26 + (1 + ox)) * 128 + c;
#pragma unroll
  for (int t = 0; t < T_STEPS; ++t) {
    va += h[0]; vb += h[1]; vc += h[2]; vd += h[3];
    bool s0 = va >= 1.f, s1 = vb >= 1.f, s2 = vc >= 1.f, s3 = vd >= 1.f;
    p1[base + (size_t)t * (32 * 676 * 128)] = (s0 | s1 | s2 | s3) ? (short)0x3F80 : (short)0;
    if (s0) va = 0.f; if (s1) vb = 0.f; if (s2) vc = 0.f; if (s3) vd = 0.f;
  }
}

// conv2 implicit-im2col MFMA GEMM, fused bn2 + IF(T) + 2x2 maxpool epilogue.
// Block = (b, pool-row py, pool-quad pxq): M-tile rows r = t*16 + iy*8 + ix
// (all 8 timesteps of 4 complete pool quads). N = 128 oc. K = 9 taps x 128 ic,
// each tap hi+lo. Writes p2 spikes directly; y2 never hits HBM.
__global__ __launch_bounds__(256) void conv2_gemm(
    const short* __restrict__ p1pad, const short* __restrict__ wt_hi, const short* __restrict__ wt_lo,
    const float* __restrict__ conv2_b, const float* __restrict__ bn2_g, const float* __restrict__ bn2_b,
    const float* __restrict__ bn2_m, const float* __restrict__ bn2_v, short* __restrict__ p2) {
  __shared__ __align__(16) short lds[24576];        // A:8192  Bh:8192  Bl:8192 shorts (49152 B)
  short* ldsA = lds;
  short* ldsBh = lds + 8192;
  short* ldsBl = lds + 16384;

  const int tid = threadIdx.x;
  const int lane = tid & 63;
  const int w = tid >> 6;                           // 0..3
  const int wm = w & 1, wn = w >> 1;
  const int b = blockIdx.y;
  const int py = blockIdx.x / 3;
  const int pxq = blockIdx.x - py * 3;

  const int g = (lane & 7) ^ (lane >> 3);
  int rowofs[4], bofs[4];
#pragma unroll
  for (int j = 0; j < 4; ++j) {
    int r = w * 32 + j * 8 + (lane >> 3);
    int t = r >> 4, iy = (r >> 3) & 1, ix = r & 7;
    rowofs[j] = (((t * 32 + b) * 676) + (2 * py + iy) * 26 + (pxq * 8 + ix)) * 128 + g * 8;
    bofs[j] = r * 128 + g * 8;
  }

  f32x4 acc[4][4];
#pragma unroll
  for (int mi = 0; mi < 4; ++mi)
#pragma unroll
    for (int ni = 0; ni < 4; ++ni) acc[mi][ni] = (f32x4){0.f, 0.f, 0.f, 0.f};

#pragma unroll 1
  for (int s = 0; s < 18; ++s) {
    const int tap = s >> 1;
    const int kk = (s & 1) << 6;
    const int tapoff = ((tap / 3) * 26 + (tap % 3)) * 128;
    __syncthreads();
#pragma unroll
    for (int j = 0; j < 4; ++j) {
      lds_load16(p1pad + rowofs[j] + tapoff + kk, ldsA + (w * 32 + j * 8) * 64 + lane * 8);
    }
    const int wtoff = tap * 16384 + kk;
#pragma unroll
    for (int j = 0; j < 4; ++j) {
      lds_load16(wt_hi + wtoff + bofs[j], ldsBh + (w * 32 + j * 8) * 64 + lane * 8);
      lds_load16(wt_lo + wtoff + bofs[j], ldsBl + (w * 32 + j * 8) * 64 + lane * 8);
    }
    __syncthreads();
#pragma unroll
    for (int ks = 0; ks < 2; ++ks) {
      bf16x8 a[4], bh[4], bl[4];
      const int cch = ks * 4 + (lane >> 4);
#pragma unroll
      for (int i = 0; i < 4; ++i) {
        int r = wm * 64 + i * 16 + (lane & 15);
        a[i] = *(const bf16x8*)(ldsA + r * 64 + ((cch ^ (r & 7)) * 8));
        int n = wn * 64 + i * 16 + (lane & 15);
        bh[i] = *(const bf16x8*)(ldsBh + n * 64 + ((cch ^ (n & 7)) * 8));
        bl[i] = *(const bf16x8*)(ldsBl + n * 64 + ((cch ^ (n & 7)) * 8));
      }
#pragma unroll
      for (int mi = 0; mi < 4; ++mi)
#pragma unroll
        for (int ni = 0; ni < 4; ++ni) {
          acc[mi][ni] = __builtin_amdgcn_mfma_f32_16x16x32_bf16(a[mi], bh[ni], acc[mi][ni], 0, 0, 0);
          acc[mi][ni] = __builtin_amdgcn_mfma_f32_16x16x32_bf16(a[mi], bl[ni], acc[mi][ni], 0, 0, 0);
        }
    }
  }

  // ---- fused epilogue: bn2 fold -> LDS (half-tile) -> IF over T -> pool -> p2
  // C/D map: local row = mi*16 + (lane>>4)*4 + reg (within wm half), col = lane&15.
  float sc[4], sh[4];
#pragma unroll
  for (int ni = 0; ni < 4; ++ni) {
    int oc = wn * 64 + ni * 16 + (lane & 15);
    sc[ni] = bn2_g[oc] * rsqrtf(bn2_v[oc] + 1e-5f);
    sh[ni] = (conv2_b[oc] - bn2_m[oc]) * sc[ni] + bn2_b[oc];
  }
  float* ybuf = (float*)lds;                        // 64 rows x stride 132 (33,792 B)
  const int S = 132;                                // 132%32==4 -> 2-way banks (free)
  float vst[16];
#pragma unroll
  for (int q = 0; q < 16; ++q) vst[q] = 0.f;
  unsigned short* p2u = (unsigned short*)p2;
  __syncthreads();                                  // all MFMA LDS reads done
#pragma unroll 1
  for (int half = 0; half < 2; ++half) {
    if (wm == half) {
#pragma unroll
      for (int ni = 0; ni < 4; ++ni)
#pragma unroll
        for (int mi = 0; mi < 4; ++mi)
#pragma unroll
          for (int r = 0; r < 4; ++r) {
            int row = mi * 16 + ((lane >> 4) << 2) + r;
            int col = wn * 64 + ni * 16 + (lane & 15);
            ybuf[row * S + col] = acc[mi][ni][r] * sc[ni] + sh[ni];
          }
    }
    __syncthreads();
    if (tid < 128) {
      const int oc = tid;
#pragma unroll
      for (int tau = 0; tau < 4; ++tau) {
        int t = half * 4 + tau;
        unsigned short ov[4];
#pragma unroll
        for (int gx = 0; gx < 4; ++gx) {
          bool any = false;
#pragma unroll
          for (int iy = 0; iy < 2; ++iy)
#pragma unroll
            for (int j = 0; j < 2; ++j) {
              float xx = ybuf[(tau * 16 + iy * 8 + 2 * gx + j) * S + oc];
              int q = gx * 4 + iy * 2 + j;
              vst[q] += xx;
              bool s = vst[q] >= 1.f;
              any |= s;
              if (s) vst[q] = 0.f;
            }
          ov[gx] = any ? (unsigned short)0x3F80 : (unsigned short)0;
        }
        ushort4 o4; o4.x = ov[0]; o4.y = ov[1]; o4.z = ov[2]; o4.w = ov[3];
        *(ushort4*)(p2u + ((size_t)(t * 32 + b) * 128 + oc) * 144 + py * 12 + pxq * 4) = o4;
      }
    }
    __syncthreads();
  }
}

// fc1: M=256, N=1152 (9 tiles), K=18432 split 32 ways. A = p2 spikes bf16;
// B = fc1_w fp32 converted to hi/lo bf16 on the fly into LDS.
__global__ __launch_bounds__(512) void fc1_gemm(const short* __restrict__ p2,
                                                const float* __restrict__ fc1_w,
                                                float* __restrict__ part) {
  __shared__ __align__(16) short lds[32768];        // A:16384  Bh:8192  Bl:8192
  short* ldsA = lds;
  short* ldsBh = lds + 16384;
  short* ldsBl = lds + 24576;

  const int tid = threadIdx.x;
  const int lane = tid & 63;
  const int w = tid >> 6;                           // 0..7
  const int wm = w & 3, wn = w >> 2;
  const int n0 = blockIdx.x * 128;
  const int kb = blockIdx.y * 576;

  const int g = (lane & 7) ^ (lane >> 3);
  int aofs[4];
#pragma unroll
  for (int j = 0; j < 4; ++j) {
    int r = w * 32 + j * 8 + (lane >> 3);
    aofs[j] = r * 18432 + g * 8;
  }
  const int bn = tid >> 2;
  const int c0 = (tid & 3) * 2;
  const float* wrow = fc1_w + (size_t)(n0 + bn) * 18432 + c0 * 8;
  const int bpos0 = (c0 ^ (bn & 7)) * 8;
  const int bpos1 = ((c0 + 1) ^ (bn & 7)) * 8;

  f32x4 acc[4][4];
#pragma unroll
  for (int mi = 0; mi < 4; ++mi)
#pragma unroll
    for (int ni = 0; ni < 4; ++ni) acc[mi][ni] = (f32x4){0.f, 0.f, 0.f, 0.f};

#pragma unroll 1
  for (int s = 0; s < 9; ++s) {
    const int koff = kb + s * 64;
    __syncthreads();
#pragma unroll
    for (int j = 0; j < 4; ++j) {
      lds_load16(p2 + aofs[j] + koff, ldsA + (w * 32 + j * 8) * 64 + lane * 8);
    }
    {
      const float4* wp = (const float4*)(wrow + koff);
      float4 q0 = wp[0], q1 = wp[1], q2 = wp[2], q3 = wp[3];
      float fv[16] = {q0.x, q0.y, q0.z, q0.w, q1.x, q1.y, q1.z, q1.w,
                      q2.x, q2.y, q2.z, q2.w, q3.x, q3.y, q3.z, q3.w};
      short8 h0, h1, l0, l1;
#pragma unroll
      for (int q = 0; q < 8; ++q) {
        unsigned short hh = bf16_rne(fv[q]);
        h0[q] = (short)hh;
        l0[q] = (short)bf16_rne(fv[q] - bf16_to_f(hh));
      }
#pragma unroll
      for (int q = 0; q < 8; ++q) {
        unsigned short hh = bf16_rne(fv[8 + q]);
        h1[q] = (short)hh;
        l1[q] = (short)bf16_rne(fv[8 + q] - bf16_to_f(hh));
      }
      *(short8*)(ldsBh + bn * 64 + bpos0) = h0;
      *(short8*)(ldsBh + bn * 64 + bpos1) = h1;
      *(short8*)(ldsBl + bn * 64 + bpos0) = l0;
      *(short8*)(ldsBl + bn * 64 + bpos1) = l1;
    }
    __syncthreads();
#pragma unroll
    for (int ks = 0; ks < 2; ++ks) {
      bf16x8 a[4], bh[4], bl[4];
      const int cch = ks * 4 + (lane >> 4);
#pragma unroll
      for (int i = 0; i < 4; ++i) {
        int r = wm * 64 + i * 16 + (lane & 15);
        a[i] = *(const bf16x8*)(ldsA + r * 64 + ((cch ^ (r & 7)) * 8));
        int n = wn * 64 + i * 16 + (lane & 15);
        bh[i] = *(const bf16x8*)(ldsBh + n * 64 + ((cch ^ (n & 7)) * 8));
        bl[i] = *(const bf16x8*)(ldsBl + n * 64 + ((cch ^ (n & 7)) * 8));
      }
#pragma unroll
      for (int mi = 0; mi < 4; ++mi)
#pragma unroll
        for (int ni = 0; ni < 4; ++ni) {
          acc[mi][ni] = __builtin_amdgcn_mfma_f32_16x16x32_bf16(a[mi], bh[ni], acc[mi][ni], 0, 0, 0);
          acc[mi][ni] = __builtin_amdgcn_mfma_f32_16x16x32_bf16(a[mi], bl[ni], acc[mi][ni], 0, 0, 0);
        }
    }
  }
  const size_t pbase = (size_t)(blockIdx.y * 9 + blockIdx.x) * 32768;
#pragma unroll
  for (int ni = 0; ni < 4; ++ni) {
    int j = wn * 64 + ni * 16 + (lane & 15);
#pragma unroll
    for (int mi = 0; mi < 4; ++mi) {
#pragma unroll
      for (int r = 0; r < 4; ++r) {
        int m = wm * 64 + mi * 16 + ((lane >> 4) << 2) + r;
        part[pbase + (size_t)m * 128 + j] = acc[mi][ni][r];
      }
    }
  }
}

// split-K reduce + bias + LIF over T, writing l1 spikes directly.
__global__ __launch_bounds__(128) void fc1_reduce_lif(const float* __restrict__ part,
                                                      const float* __restrict__ fc1_b,
                                                      float* __restrict__ l1s) {
  int i = blockIdx.x * 128 + threadIdx.x;           // < 36864 : (b, n)
  int b = i / 1152, n = i - b * 1152;
  int nt = n >> 7, j = n & 127;
  float bias = fc1_b[n];
  float v = 0.f;
#pragma unroll
  for (int t = 0; t < T_STEPS; ++t) {
    int m = t * 32 + b;
    float s = bias;
#pragma unroll 8
    for (int ks = 0; ks < 32; ++ks) s += part[(((size_t)ks * 9 + nt) * 256 + m) * 128 + j];
    v += (s - v) * 0.5f;
    bool sp = v >= 1.f;
    l1s[(size_t)m * 1152 + n] = sp ? 1.f : 0.f;
    if (sp) v = 0.f;
  }
}

// fc2: [256,1152] spikes @ w2t[k][o] -> l2pre [256][128]
__global__ __launch_bounds__(128) void fc2_kernel(const float* __restrict__ l1s,
                                                  const float* __restrict__ w2t,
                                                  const float* __restrict__ b2,
                                                  float* __restrict__ l2pre) {
  __shared__ float sx[4608];
  const int tid = threadIdx.x;
  const int m0 = blockIdx.x * 4;
  for (int i = tid; i < 4608; i += 128) sx[i] = l1s[(size_t)m0 * 1152 + i];
  __syncthreads();
  float a0 = 0.f, a1 = 0.f, a2 = 0.f, a3 = 0.f;
  for (int k = 0; k < 1152; ++k) {
    float wv = w2t[k * 128 + tid];
    a0 += sx[k] * wv;
    a1 += sx[1152 + k] * wv;
    a2 += sx[2304 + k] * wv;
    a3 += sx[3456 + k] * wv;
  }
  float bb = b2[tid];
  l2pre[(size_t)(m0 + 0) * 128 + tid] = a0 + bb;
  l2pre[(size_t)(m0 + 1) * 128 + tid] = a1 + bb;
  l2pre[(size_t)(m0 + 2) * 128 + tid] = a2 + bb;
  l2pre[(size_t)(m0 + 3) * 128 + tid] = a3 + bb;
}

// LIF(l2pre) + fc3 + LIF + mean over T, one wave per (o,b). The l2 LIF chain
// is recomputed per o (7x redundant, trivial) to skip a separate kernel.
__global__ __launch_bounds__(64) void fc3_tail(const float* __restrict__ l2pre,
                                               const float* __restrict__ w3,
                                               const float* __restrict__ b3,
                                               float* __restrict__ out) {
  const int o = blockIdx.x, b = blockIdx.y;
  const int lane = threadIdx.x;
  float wa = w3[o * 128 + lane], wb = w3[o * 128 + 64 + lane];
  float bias = b3[o];
  float va = 0.f, vb = 0.f, v = 0.f, accum = 0.f;
#pragma unroll
  for (int t = 0; t < T_STEPS; ++t) {
    const float* row = l2pre + ((size_t)(t * 32 + b)) * 128;
    float xa = row[lane], xb = row[64 + lane];
    va += (xa - va) * 0.5f;
    bool sa = va >= 1.f; if (sa) va = 0.f;
    vb += (xb - vb) * 0.5f;
    bool sb = vb >= 1.f; if (sb) vb = 0.f;
    float p = (sa ? wa : 0.f) + (sb ? wb : 0.f);
#pragma unroll
    for (int msk = 32; msk > 0; msk >>= 1) p += __shfl_xor(p, msk);
    float xx = p + bias;
    v += (xx - v) * 0.5f;
    bool s = v >= 1.f;
    accum += s ? 1.f : 0.f;
    if (s) v = 0.f;
  }
  if (lane == 0) out[b * 7 + o] = accum * 0.125f;
}

// ---------------------------------------------------------------------------
extern "C" void kernel_launch(void* const* d_in, const int* in_sizes, int n_in,
                              void* d_out, int out_size, void* d_ws, size_t ws_size,
                              hipStream_t stream) {
  const float* x       = (const float*)d_in[0];
  const float* conv1_w = (const float*)d_in[1];
  const float* conv1_b = (const float*)d_in[2];
  const float* bn1_g   = (const float*)d_in[3];
  const float* bn1_b   = (const float*)d_in[4];
  const float* bn1_m   = (const float*)d_in[5];
  const float* bn1_v   = (const float*)d_in[6];
  const float* conv2_w = (const float*)d_in[7];
  const float* conv2_b = (const float*)d_in[8];
  const float* bn2_g   = (const float*)d_in[9];
  const float* bn2_b   = (const float*)d_in[10];
  const float* bn2_m   = (const float*)d_in[11];
  const float* bn2_v   = (const float*)d_in[12];
  const float* fc1_w   = (const float*)d_in[13];
  const float* fc1_b   = (const float*)d_in[14];
  const float* fc2_w   = (const float*)d_in[15];
  const float* fc2_b   = (const float*)d_in[16];
  const float* fc3_w   = (const float*)d_in[17];
  const float* fc3_b   = (const float*)d_in[18];

  char* ws = (char*)d_ws;
  short* p1pad = (short*)(ws + OFF_P1);
  float* part  = (float*)(ws + OFF_PART);
  short* wt_hi = (short*)(ws + OFF_WT);
  short* wt_lo = wt_hi + 147456;
  short* p2    = (short*)(ws + OFF_P2);
  float* w2t   = (float*)(ws + OFF_W2T);
  float* l1s   = (float*)(ws + OFF_L1S);
  float* l2pre = (float*)(ws + OFF_L2PRE);
  float* out   = (float*)d_out;

  prep<<<2752, 256, 0, stream>>>(conv2_w, fc2_w, wt_hi, wt_lo, w2t, (uint4*)p1pad);
  conv1_if_pool<<<dim3(576, 32), 128, 0, stream>>>(x, conv1_w, conv1_b, bn1_g, bn1_b, bn1_m, bn1_v, p1pad);
  conv2_gemm<<<dim3(36, 32), 256, 0, stream>>>(p1pad, wt_hi, wt_lo, conv2_b, bn2_g, bn2_b, bn2_m, bn2_v, p2);
  fc1_gemm<<<dim3(9, 32), 512, 0, stream>>>(p2, fc1_w, part);
  fc1_reduce_lif<<<288, 128, 0, stream>>>(part, fc1_b, l1s);
  fc2_kernel<<<64, 128, 0, stream>>>(l1s, w2t, fc2_b, l2pre);
  fc3_tail<<<dim3(7, 32), 64, 0, stream>>>(l2pre, fc3_w, fc3_b, out);
}